// Round 11
// baseline (112.400 us; speedup 1.0000x reference)
//
#include <hip/hip_runtime.h>

#define HH 3500
#define WW 2500
#define TXs 64
#define TYs 16
#define KT 3                      // tiles per block (vertical)
#define WIN_H 24                  // rows ry0 .. ry0+23, ry0 = ty0-4
#define WIN_W 76                  // cols cx0 .. cx0+75, cx0 = tx0-4 (19 float4s)
#define WIN_W4 19
#define PLANE (WIN_H*WIN_W4)      // 456 quads per channel
#define NSTG (3*PLANE)            // 1368 quads per window
#define NTX 40
#define NTYG 73                   // 219 y-tiles / KT
#define NXCD 8

typedef float f32x4 __attribute__((ext_vector_type(4)));

__global__ __launch_bounds__(256, 3) void st_warp_v11(
    const float* __restrict__ src,   // [3, H, W]
    const float* __restrict__ flow,  // [2, H, W]
    float* __restrict__ out)         // [3*H*W] warped ++ [H*W*2] norm_grid
{
    __shared__ float sm[2][3][WIN_H][WIN_W];   // 43,776 B -> 3 blocks/CU

    const int nwg = NTX * NTYG;             // 2920 (div by 8)
    const int cpx = nwg / NXCD;             // 365
    const int bid = blockIdx.x;
    const int sbid = (bid % NXCD) * cpx + bid / NXCD;  // bijective XCD chunking
    const int xt = sbid / NTYG;             // column-major: vertical groups adjacent
    const int yg = sbid - xt * NTYG;

    const int tx0  = xt * TXs;
    const int ty00 = yg * (KT * TYs);       // first tile's top row
    const int cx0  = tx0 - 4;               // mult of 4 -> 16B-aligned staging
    const int wxlo = max(cx0, 0);
    const int wxhi = min(cx0 + WIN_W - 1, WW - 1);

    const long HW = (long)HH * WW;
    const int tid = threadIdx.x;
    const bool colsafe = (cx0 >= 0) && (cx0 + WIN_W <= WW);

    // constant per-thread staging decomposition (static-indexed -> registers)
    int sc[6], srr[6], sv4[6];
#pragma unroll
    for (int i = 0; i < 6; ++i) {
        const int e = tid + i * 256;
        const int c = e / PLANE;
        const int rem = e - c * PLANE;
        const int rr = rem / WIN_W4;
        sc[i] = c; srr[i] = rr; sv4[i] = (rem - rr * WIN_W4) * 4;
    }

    const int r  = tid >> 4;                 // 0..15
    const int xb = tx0 + (tid & 15) * 4;     // 16B-aligned pixel quad

    // ---------- staging helpers ----------
    auto stage_load = [&](int ty0, f32x4* pre) {
        const int ry0 = ty0 - 4;
#pragma unroll
        for (int i = 0; i < 6; ++i) {
            if (tid + i * 256 < NSTG) {
                int gy = ry0 + srr[i]; gy = min(max(gy, 0), HH - 1);
                pre[i] = *reinterpret_cast<const f32x4*>(
                    src + (long)sc[i] * HW + (long)gy * WW + (cx0 + sv4[i]));
            }
        }
    };
    auto stage_write = [&](int b, const f32x4* pre) {
#pragma unroll
        for (int i = 0; i < 6; ++i) {
            if (tid + i * 256 < NSTG) {
                *reinterpret_cast<f32x4*>(&sm[b][sc[i]][srr[i]][sv4[i]]) = pre[i];
            }
        }
    };
    auto stage_direct = [&](int b, int ty0) {     // x-border blocks only (2/40)
        const int ry0 = ty0 - 4;
        for (int e = tid; e < 3 * WIN_H * WIN_W; e += 256) {
            const int c = e / (WIN_H * WIN_W);
            const int rem = e - c * (WIN_H * WIN_W);
            const int rr = rem / WIN_W;
            const int j = rem - rr * WIN_W;
            int gy = ry0 + rr; gy = min(max(gy, 0), HH - 1);
            int gx = cx0 + j;  gx = min(max(gx, 0), WW - 1);
            sm[b][c][rr][j] = src[(long)c * HW + (long)gy * WW + gx];
        }
    };

    // ---------- per-tile compute ----------
    auto compute = [&](int ty0, int b, f32x4 fx4, f32x4 fy4) {
        const int y = ty0 + r;
        if (xb >= WW || y >= HH) return;    // quads all-in/all-out (WW%4==0)
        const int ry0 = ty0 - 4;
        const int wylo = max(ry0, 0);
        const int wyhi = min(ry0 + WIN_H - 1, HH - 1);
        const long idx = (long)y * WW + xb;

        float w00[4], w10[4], w01[4], w11[4];
        float ngv[8];
        int   lb[4], p0[4], p1[4];
        int   inwin_mask = 0;

#pragma unroll
        for (int k = 0; k < 4; ++k) {
            const int x = xb + k;
            const float gx = fx4[k] + (float)x;
            const float gy = fy4[k] + (float)y;

            const float nx = 2.0f * gx / (float)(WW - 1) - 1.0f;
            const float ny = 2.0f * gy / (float)(HH - 1) - 1.0f;
            ngv[2 * k]     = nx;
            ngv[2 * k + 1] = ny;

            // un-normalize exactly as reference (round-trip preserved)
            const float ixp = (nx + 1.0f) * 0.5f * (float)(WW - 1);
            const float iyp = (ny + 1.0f) * 0.5f * (float)(HH - 1);

            const float x0f = floorf(ixp), y0f = floorf(iyp);
            const float wx1 = ixp - x0f, wx0 = 1.0f - wx1;
            const float wy1 = iyp - y0f, wy0 = 1.0f - wy1;

            const int x0 = (int)x0f, y0i = (int)y0f;
            const int x1 = x0 + 1,  y1i = y0i + 1;

            const bool vx0 = (x0  >= 0) & (x0  < WW);
            const bool vx1 = (x1  >= 0) & (x1  < WW);
            const bool vy0 = (y0i >= 0) & (y0i < HH);
            const bool vy1 = (y1i >= 0) & (y1i < HH);

            w00[k] = wx0 * wy0 * ((vx0 & vy0) ? 1.0f : 0.0f);
            w10[k] = wx1 * wy0 * ((vx1 & vy0) ? 1.0f : 0.0f);
            w01[k] = wx0 * wy1 * ((vx0 & vy1) ? 1.0f : 0.0f);
            w11[k] = wx1 * wy1 * ((vx1 & vy1) ? 1.0f : 0.0f);

            const int x0c = min(max(x0,  0), WW - 1);
            const int y0c = min(max(y0i, 0), HH - 1);
            const int x1c = min(max(x1,  0), WW - 1);
            const int y1c = min(max(y1i, 0), HH - 1);
            p0[k] = (y0c << 16) | x0c;
            p1[k] = (y1c << 16) | x1c;

            // hot path: ALL FOUR corners in-image AND in-window -> no clamping
            const bool inwin = (x0 >= wxlo) & (x1 <= wxhi) &
                               (y0i >= wylo) & (y1i <= wyhi);
            inwin_mask |= (inwin ? 1 : 0) << k;

            lb[k] = (y0i - ry0) * WIN_W + (x0 - cx0);
        }

#pragma unroll
        for (int c = 0; c < 3; ++c) {
            const float* __restrict__ buf = &sm[b][c][0][0];
            float o[4];
#pragma unroll
            for (int k = 0; k < 4; ++k) {
                if ((inwin_mask >> k) & 1) {
                    const float* bp = buf + lb[k];
                    o[k] = bp[0] * w00[k] + bp[1] * w10[k]
                         + bp[WIN_W] * w01[k] + bp[WIN_W + 1] * w11[k];
                } else {
                    const int x0c = p0[k] & 0xffff, y0c = p0[k] >> 16;
                    const int x1c = p1[k] & 0xffff, y1c = p1[k] >> 16;
                    const float* __restrict__ s = src + (long)c * HW;
                    o[k] = s[(long)y0c * WW + x0c] * w00[k]
                         + s[(long)y0c * WW + x1c] * w10[k]
                         + s[(long)y1c * WW + x0c] * w01[k]
                         + s[(long)y1c * WW + x1c] * w11[k];
                }
            }
            f32x4 v = {o[0], o[1], o[2], o[3]};
            __builtin_nontemporal_store(v, reinterpret_cast<f32x4*>(out + (long)c * HW + idx));
        }
        float* ngbase = out + 3 * HW + 2 * idx;     // [H, W, 2] interleaved
        f32x4 n0 = {ngv[0], ngv[1], ngv[2], ngv[3]};
        f32x4 n1 = {ngv[4], ngv[5], ngv[6], ngv[7]};
        __builtin_nontemporal_store(n0, reinterpret_cast<f32x4*>(ngbase));
        __builtin_nontemporal_store(n1, reinterpret_cast<f32x4*>(ngbase + 4));
    };

    // ---------- prologue: tile 0 ----------
    f32x4 fcx = {0,0,0,0}, fcy = {0,0,0,0};
    {
        const int y0t = ty00 + r;
        if (xb < WW && y0t < HH) {
            const long id0 = (long)y0t * WW + xb;
            fcx = *reinterpret_cast<const f32x4*>(flow + id0);
            fcy = *reinterpret_cast<const f32x4*>(flow + HW + id0);
        }
        if (colsafe) { f32x4 pre[6]; stage_load(ty00, pre); stage_write(0, pre); }
        else         { stage_direct(0, ty00); }
    }
    __syncthreads();

    // ---------- pipelined tile loop ----------
#pragma unroll
    for (int t = 0; t < KT; ++t) {
        const int b = t & 1;
        f32x4 pre[6];
        f32x4 fnx = {0,0,0,0}, fny = {0,0,0,0};

        if (t < KT - 1) {
            const int tyn = ty00 + (t + 1) * TYs;
            if (colsafe) stage_load(tyn, pre);      // async: regs, no use yet
            else         stage_direct(b ^ 1, tyn);  // border blocks: direct
            const int yn = tyn + r;
            if (xb < WW && yn < HH) {
                const long idn = (long)yn * WW + xb;
                fnx = *reinterpret_cast<const f32x4*>(flow + idn);
                fny = *reinterpret_cast<const f32x4*>(flow + HW + idn);
            }
        }

        compute(ty00 + t * TYs, b, fcx, fcy);       // hides the loads above

        if (t < KT - 1) {
            if (colsafe) stage_write(b ^ 1, pre);   // waitcnt lands after compute
            fcx = fnx; fcy = fny;
            __syncthreads();
        }
    }
}

extern "C" void kernel_launch(void* const* d_in, const int* in_sizes, int n_in,
                              void* d_out, int out_size, void* d_ws, size_t ws_size,
                              hipStream_t stream) {
    const float* src  = (const float*)d_in[0];
    const float* flow = (const float*)d_in[1];
    float* out = (float*)d_out;
    (void)d_ws; (void)ws_size; (void)in_sizes; (void)n_in; (void)out_size;

    dim3 block(256, 1, 1);
    dim3 grid(NTX * NTYG, 1, 1);
    st_warp_v11<<<grid, block, 0, stream>>>(src, flow, out);
}

// Round 12
// 106.172 us; speedup vs baseline: 1.0587x; 1.0587x over previous
//
#include <hip/hip_runtime.h>

#define HH 3500
#define WW 2500
#define TXs 64
#define TYs 16
#define WIN_H 24                  // rows ry0 .. ry0+23, ry0 = ty0-4
#define WIN_W 76                  // cols cx0 .. cx0+75, cx0 = tx0-4
#define WIN_W4 19
#define ROWW (WIN_W*4)            // 304 words per LDS row (channel-interleaved)
#define NUNIT (WIN_H*WIN_W4)      // 456 staging units (row, col-quad)
#define NTX 40
#define NTY 219
#define NXCD 8

typedef float f32x4 __attribute__((ext_vector_type(4)));

// bijective word swizzle: spreads the 16-word lane stride across all 8 bank-quads
__device__ __forceinline__ int swz(int q) {
    return (q << 2) ^ (q & 8) ^ ((q & 16) >> 2);
}

__global__ __launch_bounds__(256, 5) void st_warp_v12(
    const float* __restrict__ src,   // [3, H, W]
    const float* __restrict__ flow,  // [2, H, W]
    float* __restrict__ out)         // [3*H*W] warped ++ [H*W*2] norm_grid
{
    __shared__ float smw[WIN_H * ROWW];     // 29,184 B -> 5 blocks/CU

    const int nwg = NTX * NTY;              // 8760 (div by 8)
    const int cpx = nwg / NXCD;
    const int bid = blockIdx.x;
    const int sbid = (bid % NXCD) * cpx + bid / NXCD;  // bijective XCD chunking
    const int xt = sbid / NTY;              // column-major tile order
    const int yt = sbid - xt * NTY;

    const int tx0 = xt * TXs;
    const int ty0 = yt * TYs;
    const int cx0 = tx0 - 4;                // mult of 4 -> 16B-aligned staging
    const int ry0 = ty0 - 4;

    const int wxlo = max(cx0, 0);
    const int wxhi = min(cx0 + WIN_W - 1, WW - 1);
    const int wylo = max(ry0, 0);
    const int wyhi = min(ry0 + WIN_H - 1, HH - 1);

    const long HW = (long)HH * WW;
    const int tid = threadIdx.x;
    const bool colsafe = (cx0 >= 0) && (cx0 + WIN_W <= WW);

    // ---- per-pixel identity coords ----
    const int r  = tid >> 4;                 // 0..15
    const int xb = tx0 + (tid & 15) * 4;     // 16B-aligned pixel quad
    const int y  = ty0 + r;
    const bool active = (xb < WW) && (y < HH);  // quads all-in/all-out (WW%4==0)
    const long idx = (long)y * WW + xb;

    // flow loads first (nontemporal: single-use, keep L3 for src)
    f32x4 fx4 = {0,0,0,0}, fy4 = {0,0,0,0};
    if (active) {
        fx4 = __builtin_nontemporal_load(reinterpret_cast<const f32x4*>(flow + idx));
        fy4 = __builtin_nontemporal_load(reinterpret_cast<const f32x4*>(flow + HW + idx));
    }

    // ---- staging: transpose to channel-interleaved swizzled LDS ----
    if (colsafe) {
#pragma unroll
        for (int i = 0; i < 2; ++i) {
            const int u = tid + i * 256;
            if (u < NUNIT) {
                const int rr = u / WIN_W4;
                const int v  = u - rr * WIN_W4;
                int gy = ry0 + rr; gy = min(max(gy, 0), HH - 1);
                const float* base = src + (long)gy * WW + (cx0 + 4 * v);
                const f32x4 a = *reinterpret_cast<const f32x4*>(base);
                const f32x4 b = *reinterpret_cast<const f32x4*>(base + HW);
                const f32x4 c = *reinterpret_cast<const f32x4*>(base + 2 * HW);
                const int q0 = 4 * v;
                const int wbase = rr * ROWW;
#pragma unroll
                for (int j = 0; j < 4; ++j) {
                    f32x4 t = {a[j], b[j], c[j], 0.0f};
                    *reinterpret_cast<f32x4*>(&smw[wbase + swz(q0 + j)]) = t;
                }
            }
        }
    } else {
        for (int e = tid; e < WIN_H * WIN_W; e += 256) {
            const int rr = e / WIN_W;
            const int q  = e - rr * WIN_W;
            int gy = ry0 + rr; gy = min(max(gy, 0), HH - 1);
            int gx = cx0 + q;  gx = min(max(gx, 0), WW - 1);
            const int w = rr * ROWW + swz(q);
#pragma unroll
            for (int c = 0; c < 3; ++c)
                smw[w + c] = src[(long)c * HW + (long)gy * WW + gx];
        }
    }

    // ---- weights/coords BEFORE the barrier (pure VALU, overlaps staging) ----
    float w00[4], w10[4], w01[4], w11[4];
    float ngv[8];
    int   lw[4];        // swizzled LDS word of top-left corner triplet
    int   lw1[4];       // swizzled LDS word of top-right corner triplet
    int   p0[4], p1[4]; // true clamped corners for cold path
    int   inwin_mask = 0;

    if (active) {
#pragma unroll
        for (int k = 0; k < 4; ++k) {
            const int x = xb + k;
            const float gx = fx4[k] + (float)x;
            const float gy = fy4[k] + (float)y;

            const float nx = 2.0f * gx / (float)(WW - 1) - 1.0f;
            const float ny = 2.0f * gy / (float)(HH - 1) - 1.0f;
            ngv[2 * k]     = nx;
            ngv[2 * k + 1] = ny;

            // un-normalize exactly as reference (round-trip preserved)
            const float ixp = (nx + 1.0f) * 0.5f * (float)(WW - 1);
            const float iyp = (ny + 1.0f) * 0.5f * (float)(HH - 1);

            const float x0f = floorf(ixp), y0f = floorf(iyp);
            const float wx1 = ixp - x0f, wx0 = 1.0f - wx1;
            const float wy1 = iyp - y0f, wy0 = 1.0f - wy1;

            const int x0 = (int)x0f, y0i = (int)y0f;
            const int x1 = x0 + 1,  y1i = y0i + 1;

            const bool vx0 = (x0  >= 0) & (x0  < WW);
            const bool vx1 = (x1  >= 0) & (x1  < WW);
            const bool vy0 = (y0i >= 0) & (y0i < HH);
            const bool vy1 = (y1i >= 0) & (y1i < HH);

            w00[k] = wx0 * wy0 * ((vx0 & vy0) ? 1.0f : 0.0f);
            w10[k] = wx1 * wy0 * ((vx1 & vy0) ? 1.0f : 0.0f);
            w01[k] = wx0 * wy1 * ((vx0 & vy1) ? 1.0f : 0.0f);
            w11[k] = wx1 * wy1 * ((vx0 || true ? (vx1 & vy1) : false) ? 1.0f : 0.0f);

            const int x0c = min(max(x0,  0), WW - 1);
            const int y0c = min(max(y0i, 0), HH - 1);
            const int x1c = min(max(x1,  0), WW - 1);
            const int y1c = min(max(y1i, 0), HH - 1);
            p0[k] = (y0c << 16) | x0c;
            p1[k] = (y1c << 16) | x1c;

            // hot path: ALL FOUR corners in-image AND in-window -> no clamping
            const bool inwin = (x0 >= wxlo) & (x1 <= wxhi) &
                               (y0i >= wylo) & (y1i <= wyhi);
            inwin_mask |= (inwin ? 1 : 0) << k;

            const int rr = y0i - ry0;
            const int q0 = x0 - cx0;
            lw[k]  = rr * ROWW + swz(q0);
            lw1[k] = rr * ROWW + swz(q0 + 1);
        }
    }

    __syncthreads();   // the ONLY barrier

    if (!active) return;

    float o0[4], o1[4], o2[4];
#pragma unroll
    for (int k = 0; k < 4; ++k) {
        f32x4 ov;
        if ((inwin_mask >> k) & 1) {
            const f32x4 c00 = *reinterpret_cast<const f32x4*>(&smw[lw[k]]);
            const f32x4 c10 = *reinterpret_cast<const f32x4*>(&smw[lw1[k]]);
            const f32x4 c01 = *reinterpret_cast<const f32x4*>(&smw[lw[k]  + ROWW]);
            const f32x4 c11 = *reinterpret_cast<const f32x4*>(&smw[lw1[k] + ROWW]);
            ov = c00 * w00[k] + c10 * w10[k] + c01 * w01[k] + c11 * w11[k];
        } else {
            // cold path: true clamped corners with stored weights
            const int x0c = p0[k] & 0xffff, y0c = p0[k] >> 16;
            const int x1c = p1[k] & 0xffff, y1c = p1[k] >> 16;
            const long o00 = (long)y0c * WW + x0c, o10 = (long)y0c * WW + x1c;
            const long o01 = (long)y1c * WW + x0c, o11 = (long)y1c * WW + x1c;
#pragma unroll
            for (int c = 0; c < 3; ++c) {
                const float* __restrict__ s = src + (long)c * HW;
                ov[c] = s[o00] * w00[k] + s[o10] * w10[k]
                      + s[o01] * w01[k] + s[o11] * w11[k];
            }
        }
        o0[k] = ov[0]; o1[k] = ov[1]; o2[k] = ov[2];
    }

    // ---- vectorized NT stores ----
    f32x4 v0 = {o0[0], o0[1], o0[2], o0[3]};
    f32x4 v1 = {o1[0], o1[1], o1[2], o1[3]};
    f32x4 v2 = {o2[0], o2[1], o2[2], o2[3]};
    __builtin_nontemporal_store(v0, reinterpret_cast<f32x4*>(out + idx));
    __builtin_nontemporal_store(v1, reinterpret_cast<f32x4*>(out + HW + idx));
    __builtin_nontemporal_store(v2, reinterpret_cast<f32x4*>(out + 2 * HW + idx));
    float* ngbase = out + 3 * HW + 2 * idx;     // [H, W, 2] interleaved
    f32x4 n0 = {ngv[0], ngv[1], ngv[2], ngv[3]};
    f32x4 n1 = {ngv[4], ngv[5], ngv[6], ngv[7]};
    __builtin_nontemporal_store(n0, reinterpret_cast<f32x4*>(ngbase));
    __builtin_nontemporal_store(n1, reinterpret_cast<f32x4*>(ngbase + 4));
}

extern "C" void kernel_launch(void* const* d_in, const int* in_sizes, int n_in,
                              void* d_out, int out_size, void* d_ws, size_t ws_size,
                              hipStream_t stream) {
    const float* src  = (const float*)d_in[0];
    const float* flow = (const float*)d_in[1];
    float* out = (float*)d_out;
    (void)d_ws; (void)ws_size; (void)in_sizes; (void)n_in; (void)out_size;

    dim3 block(256, 1, 1);
    dim3 grid(NTX * NTY, 1, 1);
    st_warp_v12<<<grid, block, 0, stream>>>(src, flow, out);
}

// Round 13
// 100.182 us; speedup vs baseline: 1.1220x; 1.0598x over previous
//
#include <hip/hip_runtime.h>

#define HH 3500
#define WW 2500
#define TXs 64
#define TYs 16
#define WIN_H 24                  // rows ry0 .. ry0+23, ry0 = ty0-4
#define WIN_W 76                  // pixel columns cx0 .. cx0+75
#define WIN_WP 77                 // LDS row stride in words (ODD -> bank decorrelation)
#define WIN_W4 19                 // 76/4 staging quads per row
#define NSTG (3*WIN_H*WIN_W4)     // 1368 staging units
#define NTX 40
#define NTY 219
#define NXCD 8

typedef float f32x4 __attribute__((ext_vector_type(4)));

__global__ __launch_bounds__(256, 7) void st_warp_v13(
    const float* __restrict__ src,   // [3, H, W]
    const float* __restrict__ flow,  // [2, H, W]
    float* __restrict__ out)         // [3*H*W] warped ++ [H*W*2] norm_grid
{
    __shared__ float sm[3][WIN_H][WIN_WP];  // 22,176 B -> 7 blocks/CU

    const int nwg = NTX * NTY;              // 8760 (div by 8)
    const int cpx = nwg / NXCD;
    const int bid = blockIdx.x;
    const int sbid = (bid % NXCD) * cpx + bid / NXCD;  // bijective XCD chunking
    const int xt = sbid / NTY;              // column-major tile order
    const int yt = sbid - xt * NTY;

    const int tx0 = xt * TXs;
    const int ty0 = yt * TYs;
    const int cx0 = tx0 - 4;                // mult of 4 -> 16B-aligned global loads
    const int ry0 = ty0 - 4;

    const int wxlo = max(cx0, 0);
    const int wxhi = min(cx0 + WIN_W - 1, WW - 1);
    const int wylo = max(ry0, 0);
    const int wyhi = min(ry0 + WIN_H - 1, HH - 1);

    const long HW = (long)HH * WW;
    const int tid = threadIdx.x;
    const bool colsafe = (cx0 >= 0) && (cx0 + WIN_W <= WW);

    // ---- per-pixel identity coords ----
    const int r  = tid >> 4;                 // 0..15
    const int xb = tx0 + (tid & 15) * 4;     // 16B-aligned pixel quad
    const int y  = ty0 + r;
    const bool active = (xb < WW) && (y < HH);  // quads all-in/all-out (WW%4==0)
    const long idx = (long)y * WW + xb;

    // flow loads issued first (independent of staging)
    f32x4 fx4 = {0,0,0,0}, fy4 = {0,0,0,0};
    if (active) {
        fx4 = *reinterpret_cast<const f32x4*>(flow + idx);
        fy4 = *reinterpret_cast<const f32x4*>(flow + HW + idx);
    }

    // ---- monolithic staging: all 3 channels, one barrier total ----
    if (colsafe) {
#pragma unroll
        for (int i = 0; i < 6; ++i) {
            const int e = tid + i * 256;
            if (e < NSTG) {
                const int c   = e / (WIN_H * WIN_W4);
                const int rem = e - c * (WIN_H * WIN_W4);
                const int rr  = rem / WIN_W4;
                const int v   = rem - rr * WIN_W4;
                int gy = ry0 + rr; gy = min(max(gy, 0), HH - 1);
                const f32x4 val = *reinterpret_cast<const f32x4*>(
                    src + (long)c * HW + (long)gy * WW + (cx0 + 4 * v));
                // scalar LDS writes (stride 77 breaks 16B alignment; banks decorrelate)
#pragma unroll
                for (int j = 0; j < 4; ++j)
                    sm[c][rr][4 * v + j] = val[j];
            }
        }
    } else {
        for (int e = tid; e < 3 * WIN_H * WIN_W; e += 256) {
            const int c   = e / (WIN_H * WIN_W);
            const int rem = e - c * (WIN_H * WIN_W);
            const int rr  = rem / WIN_W;
            const int j   = rem - rr * WIN_W;
            int gy = ry0 + rr; gy = min(max(gy, 0), HH - 1);
            int gx = cx0 + j;  gx = min(max(gx, 0), WW - 1);
            sm[c][rr][j] = src[(long)c * HW + (long)gy * WW + gx];
        }
    }

    // ---- weights/coords BEFORE the barrier (pure VALU, overlaps staging) ----
    float w00[4], w10[4], w01[4], w11[4];
    float ngv[8];
    int   lb[4];        // LDS word offset of top-left corner (hot path)
    int   p0[4];        // packed (y0c<<16)|x0c  — true clamped corner 0
    int   p1[4];        // packed (y1c<<16)|x1c  — true clamped corner 1
    int   inwin_mask = 0;

    if (active) {
#pragma unroll
        for (int k = 0; k < 4; ++k) {
            const int x = xb + k;
            const float gx = fx4[k] + (float)x;
            const float gy = fy4[k] + (float)y;

            const float nx = 2.0f * gx / (float)(WW - 1) - 1.0f;
            const float ny = 2.0f * gy / (float)(HH - 1) - 1.0f;
            ngv[2 * k]     = nx;
            ngv[2 * k + 1] = ny;

            // un-normalize exactly as reference (round-trip preserved)
            const float ixp = (nx + 1.0f) * 0.5f * (float)(WW - 1);
            const float iyp = (ny + 1.0f) * 0.5f * (float)(HH - 1);

            const float x0f = floorf(ixp), y0f = floorf(iyp);
            const float wx1 = ixp - x0f, wx0 = 1.0f - wx1;
            const float wy1 = iyp - y0f, wy0 = 1.0f - wy1;

            const int x0 = (int)x0f, y0i = (int)y0f;
            const int x1 = x0 + 1,  y1i = y0i + 1;

            const bool vx0 = (x0  >= 0) & (x0  < WW);
            const bool vx1 = (x1  >= 0) & (x1  < WW);
            const bool vy0 = (y0i >= 0) & (y0i < HH);
            const bool vy1 = (y1i >= 0) & (y1i < HH);

            w00[k] = wx0 * wy0 * ((vx0 & vy0) ? 1.0f : 0.0f);
            w10[k] = wx1 * wy0 * ((vx1 & vy0) ? 1.0f : 0.0f);
            w01[k] = wx0 * wy1 * ((vx0 & vy1) ? 1.0f : 0.0f);
            w11[k] = wx1 * wy1 * ((vx1 & vy1) ? 1.0f : 0.0f);

            const int x0c = min(max(x0,  0), WW - 1);
            const int y0c = min(max(y0i, 0), HH - 1);
            const int x1c = min(max(x1,  0), WW - 1);
            const int y1c = min(max(y1i, 0), HH - 1);
            p0[k] = (y0c << 16) | x0c;
            p1[k] = (y1c << 16) | x1c;

            // hot path: ALL FOUR corners in-image AND in-window -> no clamping
            const bool inwin = (x0 >= wxlo) & (x1 <= wxhi) &
                               (y0i >= wylo) & (y1i <= wyhi);
            inwin_mask |= (inwin ? 1 : 0) << k;

            lb[k] = (y0i - ry0) * WIN_WP + (x0 - cx0);
        }
    }

    __syncthreads();   // the ONLY barrier

    if (!active) return;

#pragma unroll
    for (int c = 0; c < 3; ++c) {
        const float* __restrict__ buf = &sm[c][0][0];
        float o[4];
#pragma unroll
        for (int k = 0; k < 4; ++k) {
            if ((inwin_mask >> k) & 1) {
                const float* b = buf + lb[k];
                o[k] = b[0] * w00[k] + b[1] * w10[k]
                     + b[WIN_WP] * w01[k] + b[WIN_WP + 1] * w11[k];
            } else {
                // cold path: true clamped corners with stored weights
                const int x0c = p0[k] & 0xffff, y0c = p0[k] >> 16;
                const int x1c = p1[k] & 0xffff, y1c = p1[k] >> 16;
                const float* __restrict__ s = src + (long)c * HW;
                o[k] = s[(long)y0c * WW + x0c] * w00[k]
                     + s[(long)y0c * WW + x1c] * w10[k]
                     + s[(long)y1c * WW + x0c] * w01[k]
                     + s[(long)y1c * WW + x1c] * w11[k];
            }
        }
        f32x4 v = {o[0], o[1], o[2], o[3]};
        __builtin_nontemporal_store(v, reinterpret_cast<f32x4*>(out + (long)c * HW + idx));
    }
    // norm_grid [H, W, 2] interleaved — NT (never re-read; keep L3 for inputs)
    float* ngbase = out + 3 * HW + 2 * idx;
    f32x4 n0 = {ngv[0], ngv[1], ngv[2], ngv[3]};
    f32x4 n1 = {ngv[4], ngv[5], ngv[6], ngv[7]};
    __builtin_nontemporal_store(n0, reinterpret_cast<f32x4*>(ngbase));
    __builtin_nontemporal_store(n1, reinterpret_cast<f32x4*>(ngbase + 4));
}

extern "C" void kernel_launch(void* const* d_in, const int* in_sizes, int n_in,
                              void* d_out, int out_size, void* d_ws, size_t ws_size,
                              hipStream_t stream) {
    const float* src  = (const float*)d_in[0];
    const float* flow = (const float*)d_in[1];
    float* out = (float*)d_out;
    (void)d_ws; (void)ws_size; (void)in_sizes; (void)n_in; (void)out_size;

    dim3 block(256, 1, 1);
    dim3 grid(NTX * NTY, 1, 1);
    st_warp_v13<<<grid, block, 0, stream>>>(src, flow, out);
}